// Round 1
// 77.732 us; speedup vs baseline: 1.1386x; 1.1386x over previous
//
#include <hip/hip_runtime.h>
#include <hip/hip_fp16.h>

#define MODV 26
#define HALFV 13
#define NV 64
#define BV 1024

typedef float v2f __attribute__((ext_vector_type(2)));
typedef _Float16 h2 __attribute__((ext_vector_type(2)));

// ---------------------------------------------------------------------------
// Spectral representation (R4/R5). For each (l,p,i):
//   Kp[c] = sum_{k: p*k%26==c} softmax(key_param[l,i,:])[k]
// CRT split (Z26 = Z2 x Z13): S[r] = Kp[even]+Kp[odd], D[r] = Kp[even]-Kp[odd]
// 13-pt DFT: X_j = sum_r x[r] e^{-2pi i jr/13}, j=0..6 (X_0 real).
// Chain = 63 pointwise complex products + ONE inverse DFT at the end.
// Entry = 13 packed-fp16 words: w[0..6]=(S_re,D_re) j=0..6, w[7..12]=(S_im,D_im).
//
// R6: ws entry layout TRANSPOSED to word-group-major so every VMEM
// instruction in both kernels is unit-stride coalesced.
// Per (l,p), a 4096-B entry:
//   bytes [   0,1024): lane i at i*16 -> uint4 {w0,w1,w2,w3}
//   bytes [1024,2048): lane i at i*16 -> uint4 {w4,w5,w6,w7}
//   bytes [2048,3072): lane i at i*16 -> uint4 {w8,w9,w10,w11}
//   bytes [3072,3328): lane i at i*4  -> w12
//   rest pad. uint-offset of entry = (l*26+p)<<10. ws use 6.8 MB (unchanged).
// Old layout (52 B/lane at 64-B lane stride) made each load instruction touch
// 64 distinct 64-B granules (256 transactions per wave-step, 52 needed).
// New layout: 52 transactions per wave-step, all contiguous.
// ---------------------------------------------------------------------------

__device__ __forceinline__ h2 bch2(uint u) { return __builtin_bit_cast(h2, u); }
__device__ __forceinline__ uint bcu(h2 v) { return __builtin_bit_cast(uint, v); }

__device__ __forceinline__ uint packw(v2f v)
{
    uint hs = (uint)__half_as_ushort(__float2half_rn(v.x));
    uint hd = (uint)__half_as_ushort(__float2half_rn(v.y));
    return hs | (hd << 16);
}

// state (RE[0..6], IM[1..6]) *= spectrum in packed words w13[0..12]
__device__ __forceinline__ void mulspec_w(h2* __restrict__ RE,
                                          h2* __restrict__ IM,
                                          const uint* __restrict__ w13)
{
    RE[0] *= bch2(w13[0]);
#pragma unroll
    for (int j = 1; j < 7; j++) {
        h2 kr = bch2(w13[j]), ki = bch2(w13[6 + j]);
        h2 nre = RE[j] * kr - IM[j] * ki;
        h2 nim = RE[j] * ki + IM[j] * kr;
        RE[j] = nre; IM[j] = nim;
    }
}

// ---------------------------------------------------------------------------
// Kernel 1: grid (64 l-slabs x 7 p-groups) x 256. Wave w handles
// p = 4*blockIdx.y + w (skip p>=26); one statically-unrolled p-block per
// wave (wave-uniform branch -> compile-time scatter indices).
// ---------------------------------------------------------------------------
__global__ __launch_bounds__(256)
void prep_kernel(const float* __restrict__ key_param,
                 float* __restrict__ key_probs_out,
                 uint* __restrict__ ws)
{
    __shared__ float slab[NV * MODV];   // 6656 B
    int l = blockIdx.x;
    int t = threadIdx.x;
    int i = t & 63;
    int w = t >> 6;
    int p = (blockIdx.y << 2) + w;

#pragma unroll
    for (int j = 0; j < 7; j++) {
        int idx = t + j * 256;
        if (idx < NV * MODV) slab[idx] = key_param[l * NV * MODV + idx];
    }
    __syncthreads();

    float x[MODV];
    float m = -1e30f;
#pragma unroll
    for (int k = 0; k < MODV; k++) {
        x[k] = slab[i * MODV + k];
        m = fmaxf(m, x[k]);
    }
    float s = 0.f;
#pragma unroll
    for (int k = 0; k < MODV; k++) { x[k] = __expf(x[k] - m); s += x[k]; }
    float inv = 1.f / s;
#pragma unroll
    for (int k = 0; k < MODV; k++) x[k] *= inv;

    if (blockIdx.y == 0 && w == 0) {
#pragma unroll
        for (int k = 0; k < MODV; k++)
            key_probs_out[((l << 6) + i) * MODV + k] = x[k];
    }
    if (p >= MODV) return;

    float c13[HALFV], s13[HALFV];
#pragma unroll
    for (int k = 0; k < HALFV; k++) {
        float a = 0.4833219467f * (float)k;    // 2*pi/13
        __sincosf(a, &s13[k], &c13[k]);
    }

#pragma unroll
    for (int pc = 0; pc < MODV; pc++) {
        if (pc != p) continue;          // wave-uniform; one block executes

        float Kp[MODV];
#pragma unroll
        for (int c = 0; c < MODV; c++) Kp[c] = 0.f;
#pragma unroll
        for (int k = 0; k < MODV; k++) Kp[(pc * k) % MODV] += x[k];  // static

        v2f V[HALFV];                    // (S[r], D[r])
#pragma unroll
        for (int r = 0; r < HALFV; r++) {
            int c0 = (14 * r) % MODV;
            int c1 = (13 + 14 * r) % MODV;
            v2f v; v.x = Kp[c0] + Kp[c1]; v.y = Kp[c0] - Kp[c1];
            V[r] = v;
        }

        uint hw[HALFV];
        {   // j = 0 (DC, real)
            v2f acc = V[0];
#pragma unroll
            for (int r = 1; r < HALFV; r++) acc += V[r];
            hw[0] = packw(acc);
        }
#pragma unroll
        for (int j = 1; j < 7; j++) {
            v2f re = V[0];
            v2f im; im.x = 0.f; im.y = 0.f;
#pragma unroll
            for (int r = 1; r < HALFV; r++) {
                int a = (j * r) % HALFV;            // compile-time
                re += V[r] * c13[a];
                im -= V[r] * s13[a];
            }
            hw[j]     = packw(re);
            hw[6 + j] = packw(im);
        }
        // transposed entry: all four stores below are unit-stride coalesced
        uint* dst = ws + ((size_t)(l * MODV + pc) << 10);
        *(uint4*)(dst + (i << 2))         = make_uint4(hw[0], hw[1], hw[2],  hw[3]);
        *(uint4*)(dst + 256 + (i << 2))   = make_uint4(hw[4], hw[5], hw[6],  hw[7]);
        *(uint4*)(dst + 512 + (i << 2))   = make_uint4(hw[8], hw[9], hw[10], hw[11]);
        dst[768 + i] = hw[12];
    }
}

// ---------------------------------------------------------------------------
// Kernel 2: one block (4 waves) per b. Wave w pointwise-multiplies the 16
// spectra for l in [16w,16w+16) in packed fp16, LDS tree combine (packed
// words), wave 0 does the fp32 inverse DFT + unscramble + log into LDS,
// then ALL 256 threads store the 64x26 log-prob block coalesced.
// ---------------------------------------------------------------------------
__global__ __launch_bounds__(256, 4)
void chain_kernel(const int* __restrict__ P,
                  const uint* __restrict__ ws,
                  float* __restrict__ out)
{
    __shared__ int Pl[NV];
    __shared__ uint sbuf[2][64][HALFV];  // 6656 B
    __shared__ float obuf[NV * MODV];    // 6656 B, epilogue staging

    int b = blockIdx.x;
    int w = threadIdx.x >> 6;
    int i = threadIdx.x & 63;
    if (threadIdx.x < NV) Pl[threadIdx.x] = P[(b << 6) + threadIdx.x];
    __syncthreads();

    int base = w << 4;
    int i4 = i << 2;                     // uint offset of lane's uint4

    h2 RE[7], IM[7];                     // IM[0] unused
    {
        const uint* e = ws + ((size_t)(base * MODV + Pl[base]) << 10);
        uint4 a  = *(const uint4*)(e + i4);
        uint4 bq = *(const uint4*)(e + 256 + i4);
        uint4 cq = *(const uint4*)(e + 512 + i4);
        uint w12 = e[768 + i];
        uint wd[HALFV] = {a.x, a.y, a.z, a.w, bq.x, bq.y, bq.z, bq.w,
                          cq.x, cq.y, cq.z, cq.w, w12};
#pragma unroll
        for (int j = 0; j < 7; j++) RE[j] = bch2(wd[j]);
#pragma unroll
        for (int j = 1; j < 7; j++) IM[j] = bch2(wd[6 + j]);
    }

    uint4 n0, n1, n2; uint n12;
    {
        int l = base + 1;
        const uint* e = ws + ((size_t)(l * MODV + Pl[l]) << 10);
        n0 = *(const uint4*)(e + i4);      n1 = *(const uint4*)(e + 256 + i4);
        n2 = *(const uint4*)(e + 512 + i4); n12 = e[768 + i];
    }

#pragma unroll 1
    for (int s = 1; s < 16; s++) {
        uint cw[HALFV] = {n0.x, n0.y, n0.z, n0.w, n1.x, n1.y, n1.z, n1.w,
                          n2.x, n2.y, n2.z, n2.w, n12};
        if (s < 15) {
            int l = base + s + 1;
            const uint* e = ws + ((size_t)(l * MODV + Pl[l]) << 10);
            n0 = *(const uint4*)(e + i4);      n1 = *(const uint4*)(e + 256 + i4);
            n2 = *(const uint4*)(e + 512 + i4); n12 = e[768 + i];
        }
        mulspec_w(RE, IM, cw);
    }

    // tree combine: (w0 <- w1), (w2 <- w3), then w0 <- w2 (packed words)
    if (w == 1 || w == 3) {
        int buf = w >> 1;
#pragma unroll
        for (int j = 0; j < 7; j++) sbuf[buf][i][j] = bcu(RE[j]);
#pragma unroll
        for (int j = 1; j < 7; j++) sbuf[buf][i][6 + j] = bcu(IM[j]);
    }
    __syncthreads();
    if (w == 0) {
        uint K[HALFV];
#pragma unroll
        for (int r = 0; r < HALFV; r++) K[r] = sbuf[0][i][r];
        mulspec_w(RE, IM, K);
    } else if (w == 2) {
        uint K[HALFV];
#pragma unroll
        for (int r = 0; r < HALFV; r++) K[r] = sbuf[1][i][r];
        mulspec_w(RE, IM, K);
#pragma unroll
        for (int j = 0; j < 7; j++) sbuf[1][i][j] = bcu(RE[j]);
#pragma unroll
        for (int j = 1; j < 7; j++) sbuf[1][i][6 + j] = bcu(IM[j]);
    }
    __syncthreads();
    if (w == 0) {
        uint K[HALFV];
#pragma unroll
        for (int r = 0; r < HALFV; r++) K[r] = sbuf[1][i][r];
        mulspec_w(RE, IM, K);

        // fp32 epilogue: inverse DFT (unnormalized; scale cancels), log.
        v2f fRE[7], fIM[7];
#pragma unroll
        for (int j = 0; j < 7; j++) {
            v2f v; v.x = (float)RE[j].x; v.y = (float)RE[j].y; fRE[j] = v;
        }
#pragma unroll
        for (int j = 1; j < 7; j++) {
            v2f v; v.x = (float)IM[j].x; v.y = (float)IM[j].y; fIM[j] = v;
        }

        float c13[HALFV], s13[HALFV];
#pragma unroll
        for (int k = 0; k < HALFV; k++) {
            float a = 0.4833219467f * (float)k;
            __sincosf(a, &s13[k], &c13[k]);
        }
        v2f V[HALFV];
#pragma unroll
        for (int r = 0; r < HALFV; r++) {
            v2f acc = fRE[0];
#pragma unroll
            for (int j = 1; j < 7; j++) {
                int a = (j * r) % HALFV;            // compile-time
                acc += (fRE[j] * c13[a] - fIM[j] * s13[a]) * 2.0f;
            }
            V[r] = acc;
        }

        float tot = 0.f;
#pragma unroll
        for (int r = 0; r < HALFV; r++) tot += V[r].x;
        float invt = 0.5f / tot;

        float u[MODV];
#pragma unroll
        for (int r = 0; r < HALFV; r++) {
            u[(14 * r) % MODV]      = (V[r].x + V[r].y) * invt;
            u[(13 + 14 * r) % MODV] = (V[r].x - V[r].y) * invt;
        }
#pragma unroll
        for (int c = 0; c < MODV; c++)
            obuf[i * MODV + c] = __logf(u[c] + 1e-12f);
    }
    __syncthreads();

    // cooperative coalesced store of the 64x26 fp32 block (1664 floats)
    {
        float* o = out + (size_t)b * (NV * MODV);
        int t = threadIdx.x;
#pragma unroll
        for (int k = 0; k < 6; k++)
            o[t + k * 256] = obuf[t + k * 256];
        int idx = t + 1536;
        if (idx < NV * MODV) o[idx] = obuf[idx];
    }
}

extern "C" void kernel_launch(void* const* d_in, const int* in_sizes, int n_in,
                              void* d_out, int out_size, void* d_ws, size_t ws_size,
                              hipStream_t stream)
{
    const int*   P  = (const int*)d_in[0];      // (1024, 64) int32
    const float* kp = (const float*)d_in[1];    // (4096, 26) fp32
    float* out = (float*)d_out;                 // log_probs ++ key_probs
    float* key_probs_out = out + (size_t)BV * NV * MODV;
    uint* ws = (uint*)d_ws;                     // 6,815,744 B used

    hipLaunchKernelGGL(prep_kernel, dim3(64, 7), dim3(256), 0, stream,
                       kp, key_probs_out, ws);
    hipLaunchKernelGGL(chain_kernel, dim3(BV), dim3(256), 0, stream,
                       P, ws, out);
}